// Round 10
// baseline (389.282 us; speedup 1.0000x reference)
//
#include <hip/hip_runtime.h>
#include <hip/hip_bf16.h>

// ---------------------------------------------------------------------------
// BF_NIR_conv, round 12: r3 structure at HALF tile.  8 pixels x 4 branches
// = 32 rows/block, grid 8192.  Same phases, same per-element work, same
// register profile (smaller: uu[4], 4 h1 iters) — LDS 42.5 -> 22.3 KB ->
// ~6-7 blocks/CU (24+ waves vs 12).  Occupancy via geometry, not allocator
// tricks (r4/r6/r7/r8/r10/r11 all lost fighting the allocator).
//   G-GEMM: M=16 MFMA with upper 8 rows wasted (A rows l15&7); Gt writes
//   only rows 0..7 (quad<2).  Phase 5: wave = (M-half, N-half).
// ---------------------------------------------------------------------------

using bf16x8 = __attribute__((ext_vector_type(8))) __bf16;
using f32x4  = __attribute__((ext_vector_type(4))) float;

__device__ __forceinline__ float bf2f(unsigned short u){
  unsigned int x = ((unsigned int)u) << 16;
  return __builtin_bit_cast(float, x);
}
__device__ __forceinline__ unsigned short f2bf(float f){
  unsigned int x = __builtin_bit_cast(unsigned int, f);
  unsigned int r = x + 0x7fffu + ((x >> 16) & 1u);
  return (unsigned short)(r >> 16);
}
__device__ __forceinline__ unsigned int cvt_pk_bf16(float lo, float hi){
  unsigned int r;
  asm("v_cvt_pk_bf16_f32 %0, %1, %2" : "=v"(r) : "v"(lo), "v"(hi));
  return r;
}
__device__ __forceinline__ bf16x8 ld8(const ushort* p){
  uint4 r = *(const uint4*)p;
  return __builtin_bit_cast(bf16x8, r);
}

// 16B-chunk XOR swizzle, perm(row) = (2*row + (row>>2)) & 7.
__device__ __forceinline__ int swzA(int row, int col){   // stride 256 ushort
  int p = ((row << 1) + (row >> 2)) & 7;
  return row*256 + (col ^ (p << 3));
}
__device__ __forceinline__ int swzB(int row, int col){   // stride 128 ushort
  int p = ((row << 1) + (row >> 2)) & 7;
  return row*128 + (col ^ (p << 3));
}

struct RowMeta { int spos; float relY, relX; };
__device__ __forceinline__ RowMeta row_meta(int Y, int X, int br){
  int ivx = br >> 1, ivy = br & 1;   // branch order: (vx,vy)=(-,-),(-,+),(+,-),(+,+)
  int validY, iy; float relY;
  if (ivx == 0){ validY = (Y >= 1);   iy = (Y-1) >> 1; relY = (Y & 1) ?  0.5f :  1.5f; }
  else         { validY = (Y <= 254); iy = (Y+1) >> 1; relY = (Y & 1) ? -1.5f : -0.5f; }
  int validX, ix; float relX;
  if (ivy == 0){ validX = (X >= 1);   ix = (X-1) >> 1; relX = (X & 1) ?  0.5f :  1.5f; }
  else         { validX = (X <= 254); ix = (X+1) >> 1; relX = (X & 1) ? -1.5f : -0.5f; }
  RowMeta r;
  if (validY && validX){ r.spos = iy*128 + ix; r.relY = relY; r.relX = relX; }
  else { r.spos = -1; r.relY = (float)Y + 0.5f - 128.0f; r.relX = (float)X + 0.5f - 128.0f; }
  return r;
}

// --- k0: convert weights to bf16, transposed to [N][K] ----------------------
__global__ __launch_bounds__(256) void convert_weights(
    const float* __restrict__ W1, const float* __restrict__ W2,
    const float* __restrict__ W3,
    ushort* __restrict__ W1t,   // [256][384]
    ushort* __restrict__ W2t,   // [128][256]
    ushort* __restrict__ W3t)   // [32][128]
{
  int i = blockIdx.x*256 + threadIdx.x;           // grid = 384 blocks -> i < 98304
  { int k = i >> 8, n = i & 255; W1t[n*384 + k] = f2bf(W1[i]); }
  if (i < 32768){ int k = i >> 7, n = i & 127; W2t[n*256 + k] = f2bf(W2[i]); }
  if (i < 4096) { int k = i >> 5, n = i & 31;  W3t[n*128 + k] = f2bf(W3[i]); }
}

// --- k1: U GEMM, 512 blocks x 32-pos tiles, float4-staged full-K tile -------
__global__ __launch_bounds__(256) void u_gemm(
    const float* __restrict__ lr_guide, const float* __restrict__ feat,
    const ushort* __restrict__ W1t,
    ushort* __restrict__ U)                        // [16384][256]
{
  __shared__ ushort T[32*256];                     // [pos][k], swzA
  const int t = threadIdx.x;
  const int w = t >> 6, lane = t & 63, quad = lane >> 4, l15 = lane & 15;
  const int pos0 = blockIdx.x * 32;

  #pragma unroll
  for (int i=0; i<8; i++){
    int k  = i*32 + (t>>3);
    int p4 = (t & 7) * 4;
    const float* src = (k < 128) ? lr_guide : feat;
    float4 v = *(const float4*)&src[(size_t)(k & 127)*16384 + pos0 + p4];
    T[swzA(p4+0, k)] = f2bf(v.x);
    T[swzA(p4+1, k)] = f2bf(v.y);
    T[swzA(p4+2, k)] = f2bf(v.z);
    T[swzA(p4+3, k)] = f2bf(v.w);
  }
  __syncthreads();

  f32x4 acc[2][4];
  #pragma unroll
  for (int mt=0; mt<2; mt++)
    #pragma unroll
    for (int nt=0; nt<4; nt++) acc[mt][nt] = f32x4{0.f,0.f,0.f,0.f};

  #pragma unroll
  for (int kt=0; kt<8; kt++){
    const int ko = kt*32 + quad*8;
    bf16x8 bt[4];
    #pragma unroll
    for (int nt=0; nt<4; nt++)
      bt[nt] = ld8(&W1t[(size_t)(w*64 + nt*16 + l15)*384 + ko]);
    bf16x8 a0 = ld8(&T[swzA(l15,      ko)]);
    bf16x8 a1 = ld8(&T[swzA(16 + l15, ko)]);
    #pragma unroll
    for (int nt=0; nt<4; nt++){
      acc[0][nt] = __builtin_amdgcn_mfma_f32_16x16x32_bf16(a0, bt[nt], acc[0][nt], 0,0,0);
      acc[1][nt] = __builtin_amdgcn_mfma_f32_16x16x32_bf16(a1, bt[nt], acc[1][nt], 0,0,0);
    }
  }
  #pragma unroll
  for (int mt=0; mt<2; mt++)
    #pragma unroll
    for (int nt=0; nt<4; nt++){
      int n = w*64 + nt*16 + l15;
      #pragma unroll
      for (int r=0; r<4; r++)
        U[(size_t)(pos0 + mt*16 + quad*4 + r)*256 + n] = f2bf(acc[mt][nt][r]);
    }
}

// --- k2: fused main. 256 threads, 8 pixels x 4 branches = 32 rows -----------
__global__ __launch_bounds__(256, 3) void main_fused(
    const float* __restrict__ feat,      // [128][16384]
    const float* __restrict__ hr_guide,  // [128][65536]
    const float* __restrict__ W1,        // [386][256] fp32 (rel rows 384/385)
    const float* __restrict__ b1v,
    const float* __restrict__ b2v,
    const float* __restrict__ b3v,
    const ushort* __restrict__ U,        // [16384][256] bf16
    const ushort* __restrict__ W1t,      // [256][384] bf16 (N-major)
    const ushort* __restrict__ W2t,      // [128][256] bf16 (N-major)
    const ushort* __restrict__ W3t,      // [32][128]  bf16 (N-major)
    float* __restrict__ outp)            // [32][65536]
{
  // LDS: A1 [32][256] 16 KB (hr-stage [8][128] swzB aliased at base; h2
  // [32][128] swzB aliased after sync4) + Gt [8][256] 4 KB + w1r 2 KB +
  // gcs/wgt 0.25 KB = 22.3 KB -> ~7 blocks by LDS, ~6 by VGPR(84) = ~24
  // waves/CU (2x the 16-pixel tile).  Same phases/work as the 98us r3.
  __shared__ __align__(16) ushort A1[32*256];
  __shared__ __align__(16) ushort Gt[8*256];
  __shared__ __align__(16) float  w1r[2][256];
  __shared__ float gcs[32];
  __shared__ float wgt[32];

  const int t = threadIdx.x;
  const int w = t >> 6, lane = t & 63, quad = lane >> 4, l15 = lane & 15;
  // XCD-bijective swizzle: 8192 blocks = 8 XCDs x 1024 contiguous
  const int wg = (blockIdx.x & 7) * 1024 + (blockIdx.x >> 3);
  const int Y  = wg >> 5;
  const int X0 = (wg & 31) << 3;

  const int m   = t >> 3;            // h1 row owned by this thread (0..31)
  const int cg  = t & 7;             // interleaved cols: c = cg*8 + jj*64
  const int pix = m >> 2, br = m & 3;
  RowMeta rm = row_meta(Y, X0 + pix, br);

  // ---- phase 0: U preload, G B-frags, hr->LDS, w1r, gc ----
  uint4 uu[4];
  if (rm.spos >= 0){
    const ushort* Up = U + (size_t)rm.spos*256 + cg*8;
    #pragma unroll
    for (int jj=0; jj<4; jj++) uu[jj] = *(const uint4*)(Up + jj*64);
  } else {
    #pragma unroll
    for (int jj=0; jj<4; jj++) uu[jj] = make_uint4(0u,0u,0u,0u);
  }

  bf16x8 gb[4][4];                   // G B-fragments, hoisted (pure global)
  #pragma unroll
  for (int kt=0; kt<4; kt++)
    #pragma unroll
    for (int nt=0; nt<4; nt++)
      gb[kt][nt] = ld8(&W1t[(size_t)(w*64 + nt*16 + l15)*384 + 256 + kt*32 + quad*8]);

  {                                  // hr staging: [pix][ch] swzB at A1 base
    int ch = t >> 1, xq = t & 1;     // 256 threads cover 128 ch x 2 x-quads
    float4 v = *(const float4*)(hr_guide + (size_t)ch*65536 + Y*256 + X0 + xq*4);
    A1[swzB(xq*4+0, ch)] = f2bf(v.x);
    A1[swzB(xq*4+1, ch)] = f2bf(v.y);
    A1[swzB(xq*4+2, ch)] = f2bf(v.z);
    A1[swzB(xq*4+3, ch)] = f2bf(v.w);
  }
  w1r[0][t] = W1[384*256 + t];
  w1r[1][t] = W1[385*256 + t];

  if (t < 32){
    RowMeta g = row_meta(Y, X0 + (t>>2), t & 3);
    float gc = 0.0f;
    if (g.spos >= 0){
      int bpos = (Y>>1)*128 + ((X0 + (t>>2)) >> 1);
      #pragma unroll
      for (int cc=0; cc<3; cc++)
        gc += feat[(size_t)(124+cc)*16384 + bpos] * feat[(size_t)(124+cc)*16384 + g.spos];
    }
    gcs[t] = gc;
  }
  __syncthreads();                                   // sync1

  // ---- phase 1: softmax weights + G MFMA (M=8 valid of 16, N=256, K=128) ---
  if (t < 8){
    float g0 = gcs[t*4+0], g1 = gcs[t*4+1], g2 = gcs[t*4+2], g3 = gcs[t*4+3];
    float mx = fmaxf(fmaxf(g0,g1), fmaxf(g2,g3));
    float e0 = __expf(g0-mx), e1 = __expf(g1-mx), e2 = __expf(g2-mx), e3 = __expf(g3-mx);
    float inv = 1.0f/(e0+e1+e2+e3);
    wgt[t*4+0]=e0*inv; wgt[t*4+1]=e1*inv; wgt[t*4+2]=e2*inv; wgt[t*4+3]=e3*inv;
  }
  {
    f32x4 accg[4];
    #pragma unroll
    for (int nt=0; nt<4; nt++) accg[nt] = f32x4{0.f,0.f,0.f,0.f};
    __builtin_amdgcn_s_setprio(1);
    #pragma unroll
    for (int kt=0; kt<4; kt++){
      // A row l15 -> hr pixel (l15&7); rows 8..15 duplicate (outputs unused)
      bf16x8 a = ld8(&A1[swzB(l15 & 7, kt*32 + quad*8)]);
      #pragma unroll
      for (int nt=0; nt<4; nt++)
        accg[nt] = __builtin_amdgcn_mfma_f32_16x16x32_bf16(a, gb[kt][nt], accg[nt], 0,0,0);
    }
    __builtin_amdgcn_s_setprio(0);
    if (quad < 2){                   // C/D rows quad*4+r = 0..7 are valid
      #pragma unroll
      for (int nt=0; nt<4; nt++){
        int n = w*64 + nt*16 + l15;
        float bv = b1v[n];
        #pragma unroll
        for (int r=0; r<4; r++)
          Gt[swzA(quad*4+r, n)] = f2bf(accg[nt][r] + bv);
      }
    }
  }
  __syncthreads();                                   // sync2

  // ---- phase 2: b2f hoist (global) + h1 assembly into A1 ----
  bf16x8 b2f[8][2];
  #pragma unroll
  for (int kt=0; kt<8; kt++)
    #pragma unroll
    for (int nt=0; nt<2; nt++)
      b2f[kt][nt] = ld8(&W2t[(size_t)(w*32 + nt*16 + l15)*256 + kt*32 + quad*8]);

  {
    const float relY = rm.relY, relX = rm.relX;
    #pragma unroll
    for (int jj=0; jj<4; jj++){
      const int c = cg*8 + jj*64;
      union { uint4 v; ushort s[8]; } gu, uv;
      gu.v = *(const uint4*)&Gt[swzA(pix, c)];
      uv.v = uu[jj];
      float r0[8], r1[8];
      *(float4*)&r0[0] = *(const float4*)&w1r[0][c];
      *(float4*)&r0[4] = *(const float4*)&w1r[0][c+4];
      *(float4*)&r1[0] = *(const float4*)&w1r[1][c];
      *(float4*)&r1[4] = *(const float4*)&w1r[1][c+4];
      unsigned int ov[4];
      #pragma unroll
      for (int i=0; i<4; i++){
        float h0 = bf2f(uv.s[2*i+0]) + bf2f(gu.s[2*i+0]) + relY*r0[2*i+0] + relX*r1[2*i+0];
        float h1 = bf2f(uv.s[2*i+1]) + bf2f(gu.s[2*i+1]) + relY*r0[2*i+1] + relX*r1[2*i+1];
        ov[i] = cvt_pk_bf16(fmaxf(h0, 0.0f), fmaxf(h1, 0.0f));
      }
      *(uint4*)&A1[swzA(m, c)] = make_uint4(ov[0],ov[1],ov[2],ov[3]);
    }
  }
  __syncthreads();                                   // sync3

  // ---- phase 3: layer 2 [32x256]@[256x128]; wave owns 32 N-cols ----
  f32x4 acc2[2][2];
  #pragma unroll
  for (int mt=0; mt<2; mt++)
    #pragma unroll
    for (int nt=0; nt<2; nt++) acc2[mt][nt] = f32x4{0.f,0.f,0.f,0.f};

  __builtin_amdgcn_s_setprio(1);
  #pragma unroll
  for (int mt=0; mt<2; mt++)
    #pragma unroll
    for (int kt=0; kt<8; kt++){
      bf16x8 a = ld8(&A1[swzA(mt*16 + l15, kt*32 + quad*8)]);
      #pragma unroll
      for (int nt=0; nt<2; nt++)
        acc2[mt][nt] = __builtin_amdgcn_mfma_f32_16x16x32_bf16(a, b2f[kt][nt], acc2[mt][nt], 0,0,0);
    }
  __builtin_amdgcn_s_setprio(0);
  __syncthreads();                                   // sync4: A1 reads done

  // ---- phase 4: W3 preload, h2 -> A1 alias (swzB, stride 128) ----
  bf16x8 b3f[4][2];
  #pragma unroll
  for (int kt=0; kt<4; kt++)
    #pragma unroll
    for (int nt=0; nt<2; nt++)
      b3f[kt][nt] = ld8(&W3t[(size_t)(nt*16 + l15)*128 + kt*32 + quad*8]);
  {
    float bias0 = b2v[w*32 + l15], bias1 = b2v[w*32 + 16 + l15];
    #pragma unroll
    for (int mt=0; mt<2; mt++)
      #pragma unroll
      for (int nt=0; nt<2; nt++){
        int n = w*32 + nt*16 + l15;
        float bv = nt ? bias1 : bias0;
        #pragma unroll
        for (int r=0; r<4; r++)
          A1[swzB(mt*16 + quad*4 + r, n)] = f2bf(fmaxf(acc2[mt][nt][r] + bv, 0.0f));
      }
  }
  __syncthreads();                                   // sync5: h2 ready

  // ---- phase 5: layer 3 [32x128]@[128x32]; wave = (M-half, N-half) ----
  {
    const int mh = w >> 1, nh = w & 1;
    f32x4 acc3 = f32x4{0.f,0.f,0.f,0.f};
    #pragma unroll
    for (int kt=0; kt<4; kt++){
      bf16x8 a = ld8(&A1[swzB(mh*16 + l15, kt*32 + quad*8)]);
      acc3 = __builtin_amdgcn_mfma_f32_16x16x32_bf16(a, b3f[kt][nh], acc3, 0,0,0);
    }
    // row = mh*16+quad*4+r -> pixel lp=mh*4+quad, branch r; col n=nh*16+l15
    int lp = mh*4 + quad;
    int X  = X0 + lp;
    int n  = nh*16 + l15;
    float bb = b3v[n];
    float v = wgt[lp*4+0]*(acc3[0]+bb) + wgt[lp*4+1]*(acc3[1]+bb)
            + wgt[lp*4+2]*(acc3[2]+bb) + wgt[lp*4+3]*(acc3[3]+bb);
    outp[(size_t)n*65536 + (size_t)Y*256 + X] = v;
  }
}

extern "C" void kernel_launch(void* const* d_in, const int* in_sizes, int n_in,
                              void* d_out, int out_size, void* d_ws, size_t ws_size,
                              hipStream_t stream)
{
  const float* feat     = (const float*)d_in[0];
  const float* lr_guide = (const float*)d_in[1];
  const float* hr_guide = (const float*)d_in[2];
  const float* W1       = (const float*)d_in[3];
  const float* b1       = (const float*)d_in[4];
  const float* W2       = (const float*)d_in[5];
  const float* b2       = (const float*)d_in[6];
  const float* W3       = (const float*)d_in[7];
  const float* b3       = (const float*)d_in[8];
  float* outp = (float*)d_out;

  char* ws = (char*)d_ws;
  ushort* W1t = (ushort*)(ws);                          // 196608 B
  ushort* W2t = (ushort*)(ws + 196608);                 //  65536 B
  ushort* W3t = (ushort*)(ws + 262144);                 //   8192 B
  ushort* Ub  = (ushort*)(ws + 270336);                 // 8388608 B

  convert_weights<<<384, 256, 0, stream>>>(W1, W2, W3, W1t, W2t, W3t);
  u_gemm<<<512, 256, 0, stream>>>(lr_guide, feat, W1t, Ub);
  main_fused<<<8192, 256, 0, stream>>>(feat, hr_guide, W1, b1, b2, b3,
                                       Ub, W1t, W2t, W3t, outp);
}

// Round 11
// 191.750 us; speedup vs baseline: 2.0302x; 2.0302x over previous
//
#include <hip/hip_runtime.h>
#include <hip/hip_bf16.h>

// ---------------------------------------------------------------------------
// BF_NIR_conv, FINAL (= round-5 build, measured 188.9 us total / 98 us main).
// Session-verified wins included: XCD-bijective block swizzle (FETCH 39->22MB),
// chunk-XOR LDS swizzle (conflicts 12.9e6->5e6), cvt_pk bf16 pack, hoisted
// B-fragments, 512-block u_gemm.  Seven occupancy-raising variants (512-thr,
// Gt-alias x3, waves_per_eu, RMW-partial, half-tile) all regressed — this
// 3-blocks/CU / 84-VGPR operating point is the structure's optimum.
//   k0 convert : W1/W2/W3 -> bf16 N-major
//   k1 u_gemm  : U[pos][256] = featc[pos] @ W1[0:256]; 512 blocks, LDS-staged
//   k2 main    : hr staged f4->LDS, G-MFMA -> Gt, h1 assembly (cvt_pk),
//                L2/L3 MFMA with batch-hoisted fragments, 5-barrier chain
// ---------------------------------------------------------------------------

using bf16x8 = __attribute__((ext_vector_type(8))) __bf16;
using f32x4  = __attribute__((ext_vector_type(4))) float;

__device__ __forceinline__ float bf2f(unsigned short u){
  unsigned int x = ((unsigned int)u) << 16;
  return __builtin_bit_cast(float, x);
}
__device__ __forceinline__ unsigned short f2bf(float f){
  unsigned int x = __builtin_bit_cast(unsigned int, f);
  unsigned int r = x + 0x7fffu + ((x >> 16) & 1u);
  return (unsigned short)(r >> 16);
}
__device__ __forceinline__ unsigned int cvt_pk_bf16(float lo, float hi){
  unsigned int r;
  asm("v_cvt_pk_bf16_f32 %0, %1, %2" : "=v"(r) : "v"(lo), "v"(hi));
  return r;
}
__device__ __forceinline__ bf16x8 ld8(const ushort* p){
  uint4 r = *(const uint4*)p;
  return __builtin_bit_cast(bf16x8, r);
}

// 16B-chunk XOR swizzle, perm(row) = (2*row + (row>>2)) & 7.
__device__ __forceinline__ int swzA(int row, int col){   // stride 256 ushort
  int p = ((row << 1) + (row >> 2)) & 7;
  return row*256 + (col ^ (p << 3));
}
__device__ __forceinline__ int swzB(int row, int col){   // stride 128 ushort
  int p = ((row << 1) + (row >> 2)) & 7;
  return row*128 + (col ^ (p << 3));
}

struct RowMeta { int spos; float relY, relX; };
__device__ __forceinline__ RowMeta row_meta(int Y, int X, int br){
  int ivx = br >> 1, ivy = br & 1;   // branch order: (vx,vy)=(-,-),(-,+),(+,-),(+,+)
  int validY, iy; float relY;
  if (ivx == 0){ validY = (Y >= 1);   iy = (Y-1) >> 1; relY = (Y & 1) ?  0.5f :  1.5f; }
  else         { validY = (Y <= 254); iy = (Y+1) >> 1; relY = (Y & 1) ? -1.5f : -0.5f; }
  int validX, ix; float relX;
  if (ivy == 0){ validX = (X >= 1);   ix = (X-1) >> 1; relX = (X & 1) ?  0.5f :  1.5f; }
  else         { validX = (X <= 254); ix = (X+1) >> 1; relX = (X & 1) ? -1.5f : -0.5f; }
  RowMeta r;
  if (validY && validX){ r.spos = iy*128 + ix; r.relY = relY; r.relX = relX; }
  else { r.spos = -1; r.relY = (float)Y + 0.5f - 128.0f; r.relX = (float)X + 0.5f - 128.0f; }
  return r;
}

// --- k0: convert weights to bf16, transposed to [N][K] ----------------------
__global__ __launch_bounds__(256) void convert_weights(
    const float* __restrict__ W1, const float* __restrict__ W2,
    const float* __restrict__ W3,
    ushort* __restrict__ W1t,   // [256][384]
    ushort* __restrict__ W2t,   // [128][256]
    ushort* __restrict__ W3t)   // [32][128]
{
  int i = blockIdx.x*256 + threadIdx.x;           // grid = 384 blocks -> i < 98304
  { int k = i >> 8, n = i & 255; W1t[n*384 + k] = f2bf(W1[i]); }
  if (i < 32768){ int k = i >> 7, n = i & 127; W2t[n*256 + k] = f2bf(W2[i]); }
  if (i < 4096) { int k = i >> 5, n = i & 31;  W3t[n*128 + k] = f2bf(W3[i]); }
}

// --- k1: U GEMM, 512 blocks x 32-pos tiles, full-K LDS stage ----------------
__global__ __launch_bounds__(256) void u_gemm(
    const float* __restrict__ lr_guide, const float* __restrict__ feat,
    const ushort* __restrict__ W1t,
    ushort* __restrict__ U)                        // [16384][256]
{
  __shared__ ushort T[32*256];                     // [pos][k], swzA
  const int t = threadIdx.x;
  const int w = t >> 6, lane = t & 63, quad = lane >> 4, l15 = lane & 15;
  const int pos0 = blockIdx.x * 32;

  #pragma unroll
  for (int i=0; i<32; i++){                        // k = i*8 + t>>5, p = t&31
    int k = i*8 + (t>>5), p = t & 31;
    const float* src = (k < 128) ? lr_guide : feat;
    T[swzA(p, k)] = f2bf(src[(size_t)(k & 127)*16384 + pos0 + p]);
  }
  __syncthreads();

  f32x4 acc[2][4];
  #pragma unroll
  for (int mt=0; mt<2; mt++)
    #pragma unroll
    for (int nt=0; nt<4; nt++) acc[mt][nt] = f32x4{0.f,0.f,0.f,0.f};

  #pragma unroll
  for (int kt=0; kt<8; kt++){
    const int ko = kt*32 + quad*8;
    bf16x8 bt[4];
    #pragma unroll
    for (int nt=0; nt<4; nt++)
      bt[nt] = ld8(&W1t[(size_t)(w*64 + nt*16 + l15)*384 + ko]);
    bf16x8 a0 = ld8(&T[swzA(l15,      ko)]);
    bf16x8 a1 = ld8(&T[swzA(16 + l15, ko)]);
    #pragma unroll
    for (int nt=0; nt<4; nt++){
      acc[0][nt] = __builtin_amdgcn_mfma_f32_16x16x32_bf16(a0, bt[nt], acc[0][nt], 0,0,0);
      acc[1][nt] = __builtin_amdgcn_mfma_f32_16x16x32_bf16(a1, bt[nt], acc[1][nt], 0,0,0);
    }
  }
  #pragma unroll
  for (int mt=0; mt<2; mt++)
    #pragma unroll
    for (int nt=0; nt<4; nt++){
      int n = w*64 + nt*16 + l15;
      #pragma unroll
      for (int r=0; r<4; r++)
        U[(size_t)(pos0 + mt*16 + quad*4 + r)*256 + n] = f2bf(acc[mt][nt][r]);
    }
}

// --- k2: fused main. 256 threads, 16 pixels x 4 branches = 64 rows ----------
__global__ __launch_bounds__(256, 3) void main_fused(
    const float* __restrict__ feat,      // [128][16384]
    const float* __restrict__ hr_guide,  // [128][65536]
    const float* __restrict__ W1,        // [386][256] fp32 (rel rows 384/385)
    const float* __restrict__ b1v,
    const float* __restrict__ b2v,
    const float* __restrict__ b3v,
    const ushort* __restrict__ U,        // [16384][256] bf16
    const ushort* __restrict__ W1t,      // [256][384] bf16 (N-major)
    const ushort* __restrict__ W2t,      // [128][256] bf16 (N-major)
    const ushort* __restrict__ W3t,      // [32][128]  bf16 (N-major)
    float* __restrict__ outp)            // [32][65536]
{
  // LDS: A1 32 KB (hr-stage [16][128] swzB aliased at base; h2 [64][128]
  // swzB aliased after sync4) + Gt 8 KB + w1r 2 KB + gcs/wgt 0.5 KB
  // = 42.5 KB -> 3 blocks/CU.  84 VGPR, zero spill (measured).
  __shared__ __align__(16) ushort A1[64*256];
  __shared__ __align__(16) ushort Gt[16*256];
  __shared__ __align__(16) float  w1r[2][256];
  __shared__ float gcs[64];
  __shared__ float wgt[64];

  const int t = threadIdx.x;
  const int w = t >> 6, lane = t & 63, quad = lane >> 4, l15 = lane & 15;
  // XCD-bijective swizzle: 4096 blocks = 8 XCDs x 512 contiguous
  const int wg = (blockIdx.x & 7) * 512 + (blockIdx.x >> 3);
  const int Y  = wg >> 4;
  const int X0 = (wg & 15) << 4;

  const int m   = t >> 2;            // h1 row owned by this thread
  const int cg  = t & 3;             // interleaved cols: c = cg*8 + jj*32
  const int pix = m >> 2, br = m & 3;
  RowMeta rm = row_meta(Y, X0 + pix, br);

  // ---- phase 0: U preload, G B-frags (global, overlap staging), hr->LDS ----
  uint4 uu[8];
  if (rm.spos >= 0){
    const ushort* Up = U + (size_t)rm.spos*256 + cg*8;
    #pragma unroll
    for (int jj=0; jj<8; jj++) uu[jj] = *(const uint4*)(Up + jj*32);
  } else {
    #pragma unroll
    for (int jj=0; jj<8; jj++) uu[jj] = make_uint4(0u,0u,0u,0u);
  }

  bf16x8 gb[4][4];                   // G B-fragments, hoisted (pure global)
  #pragma unroll
  for (int kt=0; kt<4; kt++)
    #pragma unroll
    for (int nt=0; nt<4; nt++)
      gb[kt][nt] = ld8(&W1t[(size_t)(w*64 + nt*16 + l15)*384 + 256 + kt*32 + quad*8]);

  {                                  // hr staging: [pix][ch] swzB at A1 base
    #pragma unroll
    for (int i=0; i<2; i++){
      int id = i*256 + t;            // 0..511
      int ch = id >> 2, xq = id & 3;
      float4 v = *(const float4*)(hr_guide + (size_t)ch*65536 + Y*256 + X0 + xq*4);
      A1[swzB(xq*4+0, ch)] = f2bf(v.x);
      A1[swzB(xq*4+1, ch)] = f2bf(v.y);
      A1[swzB(xq*4+2, ch)] = f2bf(v.z);
      A1[swzB(xq*4+3, ch)] = f2bf(v.w);
    }
  }
  w1r[0][t] = W1[384*256 + t];
  w1r[1][t] = W1[385*256 + t];

  if (t < 64){
    RowMeta g = row_meta(Y, X0 + (t>>2), t & 3);
    float gc = 0.0f;
    if (g.spos >= 0){
      int bpos = (Y>>1)*128 + ((X0 + (t>>2)) >> 1);
      #pragma unroll
      for (int cc=0; cc<3; cc++)
        gc += feat[(size_t)(124+cc)*16384 + bpos] * feat[(size_t)(124+cc)*16384 + g.spos];
    }
    gcs[t] = gc;
  }
  __syncthreads();                                   // sync1

  // ---- phase 1: softmax weights + G MFMA (M=16 pix, N=256, K=128) ----
  if (t < 16){
    float g0 = gcs[t*4+0], g1 = gcs[t*4+1], g2 = gcs[t*4+2], g3 = gcs[t*4+3];
    float mx = fmaxf(fmaxf(g0,g1), fmaxf(g2,g3));
    float e0 = __expf(g0-mx), e1 = __expf(g1-mx), e2 = __expf(g2-mx), e3 = __expf(g3-mx);
    float inv = 1.0f/(e0+e1+e2+e3);
    wgt[t*4+0]=e0*inv; wgt[t*4+1]=e1*inv; wgt[t*4+2]=e2*inv; wgt[t*4+3]=e3*inv;
  }
  {
    f32x4 accg[4];
    #pragma unroll
    for (int nt=0; nt<4; nt++) accg[nt] = f32x4{0.f,0.f,0.f,0.f};
    #pragma unroll
    for (int kt=0; kt<4; kt++){
      bf16x8 a = ld8(&A1[swzB(l15, kt*32 + quad*8)]);          // hr-stage
      #pragma unroll
      for (int nt=0; nt<4; nt++)
        accg[nt] = __builtin_amdgcn_mfma_f32_16x16x32_bf16(a, gb[kt][nt], accg[nt], 0,0,0);
    }
    #pragma unroll
    for (int nt=0; nt<4; nt++){
      int n = w*64 + nt*16 + l15;
      float bv = b1v[n];
      #pragma unroll
      for (int r=0; r<4; r++)
        Gt[swzA(quad*4+r, n)] = f2bf(accg[nt][r] + bv);        // C/D row=quad*4+r
    }
  }
  __syncthreads();                                   // sync2

  // ---- phase 2: b2f hoist (global) + h1 assembly into A1 ----
  bf16x8 b2f[8][2];
  #pragma unroll
  for (int kt=0; kt<8; kt++)
    #pragma unroll
    for (int nt=0; nt<2; nt++)
      b2f[kt][nt] = ld8(&W2t[(size_t)(w*32 + nt*16 + l15)*256 + kt*32 + quad*8]);

  {
    const float relY = rm.relY, relX = rm.relX;
    #pragma unroll
    for (int jj=0; jj<8; jj++){
      const int c = cg*8 + jj*32;
      union { uint4 v; ushort s[8]; } gu, uv;
      gu.v = *(const uint4*)&Gt[swzA(pix, c)];
      uv.v = uu[jj];
      float r0[8], r1[8];
      *(float4*)&r0[0] = *(const float4*)&w1r[0][c];
      *(float4*)&r0[4] = *(const float4*)&w1r[0][c+4];
      *(float4*)&r1[0] = *(const float4*)&w1r[1][c];
      *(float4*)&r1[4] = *(const float4*)&w1r[1][c+4];
      unsigned int ov[4];
      #pragma unroll
      for (int i=0; i<4; i++){
        float h0 = bf2f(uv.s[2*i+0]) + bf2f(gu.s[2*i+0]) + relY*r0[2*i+0] + relX*r1[2*i+0];
        float h1 = bf2f(uv.s[2*i+1]) + bf2f(gu.s[2*i+1]) + relY*r0[2*i+1] + relX*r1[2*i+1];
        ov[i] = cvt_pk_bf16(fmaxf(h0, 0.0f), fmaxf(h1, 0.0f));
      }
      *(uint4*)&A1[swzA(m, c)] = make_uint4(ov[0],ov[1],ov[2],ov[3]);
    }
  }
  __syncthreads();                                   // sync3

  // ---- phase 3: layer 2 [64x256]@[256x128]; wave owns 32 N-cols ----
  f32x4 acc2[4][2];
  #pragma unroll
  for (int mt=0; mt<4; mt++)
    #pragma unroll
    for (int nt=0; nt<2; nt++) acc2[mt][nt] = f32x4{0.f,0.f,0.f,0.f};

  __builtin_amdgcn_s_setprio(1);
  #pragma unroll
  for (int mt=0; mt<4; mt++)
    #pragma unroll
    for (int kt=0; kt<8; kt++){
      bf16x8 a = ld8(&A1[swzA(mt*16 + l15, kt*32 + quad*8)]);
      #pragma unroll
      for (int nt=0; nt<2; nt++)
        acc2[mt][nt] = __builtin_amdgcn_mfma_f32_16x16x32_bf16(a, b2f[kt][nt], acc2[mt][nt], 0,0,0);
    }
  __builtin_amdgcn_s_setprio(0);
  __syncthreads();                                   // sync4: A1 reads done

  // ---- phase 4: W3 preload, h2 -> A1 alias (swzB, stride 128) ----
  bf16x8 b3f[4][2];
  #pragma unroll
  for (int kt=0; kt<4; kt++)
    #pragma unroll
    for (int nt=0; nt<2; nt++)
      b3f[kt][nt] = ld8(&W3t[(size_t)(nt*16 + l15)*128 + kt*32 + quad*8]);
  {
    float bias0 = b2v[w*32 + l15], bias1 = b2v[w*32 + 16 + l15];
    #pragma unroll
    for (int mt=0; mt<4; mt++)
      #pragma unroll
      for (int nt=0; nt<2; nt++){
        int n = w*32 + nt*16 + l15;
        float bv = nt ? bias1 : bias0;
        #pragma unroll
        for (int r=0; r<4; r++)
          A1[swzB(mt*16 + quad*4 + r, n)] = f2bf(fmaxf(acc2[mt][nt][r] + bv, 0.0f));
      }
  }
  __syncthreads();                                   // sync5: h2 ready

  // ---- phase 5: layer 3 [64x128]@[128x32] + weighted combine ----
  {
    f32x4 acc3[2] = { f32x4{0.f,0.f,0.f,0.f}, f32x4{0.f,0.f,0.f,0.f} };
    #pragma unroll
    for (int kt=0; kt<4; kt++){
      bf16x8 a = ld8(&A1[swzB(w*16 + l15, kt*32 + quad*8)]);
      #pragma unroll
      for (int nt=0; nt<2; nt++)
        acc3[nt] = __builtin_amdgcn_mfma_f32_16x16x32_bf16(a, b3f[kt][nt], acc3[nt], 0,0,0);
    }
    // row = w*16+quad*4+r -> pixel lp=w*4+quad, branch r
    int lp = w*4 + quad;
    int X = X0 + lp;
    float w0 = wgt[lp*4+0], w1 = wgt[lp*4+1], w2 = wgt[lp*4+2], w3 = wgt[lp*4+3];
    #pragma unroll
    for (int nt=0; nt<2; nt++){
      int n = nt*16 + l15;
      float bb = b3v[n];
      float v = w0*(acc3[nt][0]+bb) + w1*(acc3[nt][1]+bb)
              + w2*(acc3[nt][2]+bb) + w3*(acc3[nt][3]+bb);
      outp[(size_t)n*65536 + (size_t)Y*256 + X] = v;
    }
  }
}

extern "C" void kernel_launch(void* const* d_in, const int* in_sizes, int n_in,
                              void* d_out, int out_size, void* d_ws, size_t ws_size,
                              hipStream_t stream)
{
  const float* feat     = (const float*)d_in[0];
  const float* lr_guide = (const float*)d_in[1];
  const float* hr_guide = (const float*)d_in[2];
  const float* W1       = (const float*)d_in[3];
  const float* b1       = (const float*)d_in[4];
  const float* W2       = (const float*)d_in[5];
  const float* b2       = (const float*)d_in[6];
  const float* W3       = (const float*)d_in[7];
  const float* b3       = (const float*)d_in[8];
  float* outp = (float*)d_out;

  char* ws = (char*)d_ws;
  ushort* W1t = (ushort*)(ws);                          // 196608 B
  ushort* W2t = (ushort*)(ws + 196608);                 //  65536 B
  ushort* W3t = (ushort*)(ws + 262144);                 //   8192 B
  ushort* Ub  = (ushort*)(ws + 270336);                 // 8388608 B

  convert_weights<<<384, 256, 0, stream>>>(W1, W2, W3, W1t, W2t, W3t);
  u_gemm<<<512, 256, 0, stream>>>(lr_guide, feat, W1t, Ub);
  main_fused<<<4096, 256, 0, stream>>>(feat, hr_guide, W1, b1, b2, b3,
                                       Ub, W1t, W2t, W3t, outp);
}